// Round 14
// baseline (610.223 us; speedup 1.0000x reference)
//
#include <hip/hip_runtime.h>
#include <hip/hip_cooperative_groups.h>

namespace cg = cooperative_groups;

#define D 64
#define ED 16

// ---------------------------------------------------------------------------
// Inline int64/int32 probe (wave-uniform): int64 nonneg indices -> all odd
// dwords zero.  P(false positive on int32 random indices) ~ 0.
// ---------------------------------------------------------------------------
__device__ __forceinline__ int detect_is64(const int* __restrict__ idx32)
{
    int v = idx32[2 * (threadIdx.x & 63) + 1];
    return __all(v == 0) ? 1 : 0;
}

__device__ __forceinline__ int load_idx(const void* p, size_t i, int is64)
{
    return is64 ? (int)((const long long*)p)[i] : ((const int*)p)[i];
}

// ---------------------------------------------------------------------------
// Cooperative CSR build (round-14): the 5-dispatch chain (memset, count,
// scan1, scan3, scatter) measured 108 us while its memory work is ~30 us —
// ~70 us was dispatch/serialization overhead.  One cooperative kernel with
// grid.sync() between phases.  1024 blocks x 256 thr = 4 blocks/CU, co-
// resident at any VGPR<=128 (phases use ~40), LDS 2 KB.
// ---------------------------------------------------------------------------
__global__ void __launch_bounds__(256)
csr_build_kernel(const void* __restrict__ edge_index,
                 int* __restrict__ cnt, int* __restrict__ offs,
                 int* __restrict__ cursor, int* __restrict__ bsum,
                 int2* __restrict__ pair, int n_nodes, int n_edges)
{
    cg::grid_group grid = cg::this_grid();
    const int tid = blockIdx.x * blockDim.x + threadIdx.x;
    const int nthr = gridDim.x * blockDim.x;
    const int is64 = detect_is64((const int*)edge_index);
    const int NB = (n_nodes + 255) / 256;
    __shared__ int sd[256];

    // phase 0: zero cnt
    for (int i = tid; i < n_nodes; i += nthr) cnt[i] = 0;
    grid.sync();

    // phase 1: count (1 int atomic per edge)
    for (int e = tid; e < n_edges; e += nthr) {
        int dst = load_idx(edge_index, (size_t)n_edges + e, is64);
        atomicAdd(&cnt[dst], 1);
    }
    grid.sync();

    // phase 2a: block-local exclusive scan (first NB blocks active)
    if (blockIdx.x < NB) {
        const int t = threadIdx.x;
        const int i = blockIdx.x * 256 + t;
        int v = (i < n_nodes) ? cnt[i] : 0;
        sd[t] = v;
        __syncthreads();
        for (int off = 1; off < 256; off <<= 1) {
            int add = (t >= off) ? sd[t - off] : 0;
            __syncthreads();
            sd[t] += add;
            __syncthreads();
        }
        if (i < n_nodes) offs[i] = sd[t] - v;     // exclusive within block
        if (t == 255) bsum[blockIdx.x] = sd[t];   // block total
    }
    grid.sync();

    // phase 2b: per-block prefix of bsum, finalize offs + cursor, sentinel
    if (blockIdx.x < NB) {
        int part = 0;
        for (int j = threadIdx.x; j < blockIdx.x; j += 256) part += bsum[j];
        __syncthreads();                           // sd reuse barrier
        sd[threadIdx.x] = part;
        __syncthreads();
        for (int off = 128; off > 0; off >>= 1) {
            if (threadIdx.x < off) sd[threadIdx.x] += sd[threadIdx.x + off];
            __syncthreads();
        }
        const int S = sd[0];
        const int i = blockIdx.x * 256 + threadIdx.x;
        if (i < n_nodes) {
            int v = offs[i] + S;
            offs[i]   = v;
            cursor[i] = v;
        }
    }
    if (tid == 0) offs[n_nodes] = n_edges;         // sentinel
    grid.sync();

    // phase 3: scatter (src, eid) to sorted-by-dst positions
    for (int e = tid; e < n_edges; e += nthr) {
        int src = load_idx(edge_index, e, is64);
        int dst = load_idx(edge_index, (size_t)n_edges + e, is64);
        int pos = atomicAdd(&cursor[dst], 1);
        pair[pos] = make_int2(src, e);
    }
}

// ---------------------------------------------------------------------------
// Gather-reduce — EXACT round-9 structure (measured 97 us, VGPR 40; proven
// floor: invariant to bytes/lines/occupancy/MLP-depth — L3 random-line
// service bound).  One wave per node, grid-strided, no LDS, no barriers,
// W_e column in 16 VGPRs/lane.
//   agg_mean[i] = ( sum_e x[src_e] + (sum_e ea[e]) @ W_e + deg*b_e ) / max(deg,1)
// ---------------------------------------------------------------------------
__global__ void __launch_bounds__(256)
reduce_kernel(const float* __restrict__ x,
              const float* __restrict__ edge_attr,
              const float* __restrict__ W_e,
              const float* __restrict__ b_e,
              const int2* __restrict__ pair,
              const int* __restrict__ offs,   // n_nodes+1 (sentinel)
              float* __restrict__ agg,
              int n_nodes)
{
    const int lane = threadIdx.x & 63;
    const int wid  = threadIdx.x >> 6;
    const int sub  = lane >> 4;
    const int k16  = lane & 15;

    float Wreg[ED];
    #pragma unroll
    for (int k = 0; k < ED; ++k) Wreg[k] = W_e[k * D + lane];
    const float beL = b_e[lane];

    const int nstride = gridDim.x * 4;
    for (int node = blockIdx.x * 4 + wid; node < n_nodes; node += nstride) {
        const int beg = offs[node];
        const int deg = offs[node + 1] - beg;

        float xs  = 0.0f;
        float eas = 0.0f;

        for (int j0 = 0; j0 < deg; j0 += 16) {
            const int nb = min(16, deg - j0);       // wave-uniform
            int2 p = make_int2(0, 0);
            if (lane < nb) p = pair[beg + j0 + lane];

            float t[16];
            #pragma unroll
            for (int m = 0; m < 16; ++m) {
                int s = __shfl(p.x, m);
                t[m] = (m < nb) ? x[(size_t)s * D + lane] : 0.0f;
            }

            #pragma unroll
            for (int mm = 0; mm < 4; ++mm) {
                int m = sub + 4 * mm;
                int eid = __shfl(p.y, m);
                if (m < nb) eas += edge_attr[(size_t)eid * ED + k16];
            }

            #pragma unroll
            for (int m = 0; m < 16; ++m) xs += t[m];
        }

        float ea2 = eas + __shfl_xor(eas, 16);
        ea2 += __shfl_xor(ea2, 32);

        float acc = xs + (float)deg * beL;
        #pragma unroll
        for (int k = 0; k < ED; ++k)
            acc += __shfl(ea2, k) * Wreg[k];

        agg[(size_t)node * D + lane] = acc * (1.0f / fmaxf((float)deg, 1.0f));
    }
}

// ---------------------------------------------------------------------------
// Fallback path (ws too small): atomic scatter + divide.
// ---------------------------------------------------------------------------
__global__ void __launch_bounds__(256)
edge_scatter_kernel(const float* __restrict__ x,
                    const float* __restrict__ edge_attr,
                    const float* __restrict__ W_e,
                    const float* __restrict__ b_e,
                    const void* __restrict__ edge_index,
                    float* __restrict__ agg,
                    float* __restrict__ cnt,
                    int n_edges)
{
    __shared__ float We[ED * D];
    __shared__ float be[D];
    for (int i = threadIdx.x; i < ED * D; i += blockDim.x) We[i] = W_e[i];
    if (threadIdx.x < D) be[threadIdx.x] = b_e[threadIdx.x];
    __syncthreads();

    const int is64 = detect_is64((const int*)edge_index);
    const int lane = threadIdx.x & 63;
    const int wid  = threadIdx.x >> 6;
    const int estr = gridDim.x * 4;

    for (int e = blockIdx.x * 4 + wid; e < n_edges; e += estr) {
        int src = load_idx(edge_index, e, is64);
        int dst = load_idx(edge_index, (size_t)n_edges + e, is64);
        const float4* ea = (const float4*)(edge_attr + (size_t)e * ED);
        float4 e0 = ea[0], e1 = ea[1], e2 = ea[2], e3 = ea[3];

        float m = be[lane] + x[(size_t)src * D + lane];
        m += e0.x * We[ 0*D + lane] + e0.y * We[ 1*D + lane]
           + e0.z * We[ 2*D + lane] + e0.w * We[ 3*D + lane];
        m += e1.x * We[ 4*D + lane] + e1.y * We[ 5*D + lane]
           + e1.z * We[ 6*D + lane] + e1.w * We[ 7*D + lane];
        m += e2.x * We[ 8*D + lane] + e2.y * We[ 9*D + lane]
           + e2.z * We[10*D + lane] + e2.w * We[11*D + lane];
        m += e3.x * We[12*D + lane] + e3.y * We[13*D + lane]
           + e3.z * We[14*D + lane] + e3.w * We[15*D + lane];

        atomicAdd(&agg[(size_t)dst * D + lane], m);
        if (lane == 0) atomicAdd(&cnt[dst], 1.0f);
    }
}

__global__ void divide_kernel(float* __restrict__ agg, const float* __restrict__ cnt, int n_nodes)
{
    const int i = blockIdx.x * 256 + threadIdx.x;
    if (i < n_nodes * D) {
        float c = cnt[i >> 6];
        agg[i] *= 1.0f / fmaxf(c, 1.0f);
    }
}

// ---------------------------------------------------------------------------
// Node phase as one GEMM:  out = [agg | x] @ [W_l ; W_r] + b_l
// (register discipline per round-5 lesson: rolled s-loop, unroll 4 kk-loop,
//  __launch_bounds__(256,4) caps VGPR at 128.)  UNCHANGED.
// ---------------------------------------------------------------------------
#define BM 128
#define BK 32
#define ATP 132   // padded row length (dwords): 132*4B % 16B == 0

__global__ void __launch_bounds__(256, 4)
node_gemm_kernel(const float* x,
                 const float* agg,                // == out (in-place)
                 const float* __restrict__ W_l,
                 const float* __restrict__ b_l,
                 const float* __restrict__ W_r,
                 float* out,
                 int n_nodes)
{
    __shared__ float AT[BK][ATP];
    __shared__ float Wt[BK][D];

    const int t   = threadIdx.x;
    const int to  = t & 15;
    const int tm  = t >> 4;
    const int base = blockIdx.x * BM;

    float acc[8][4];
    #pragma unroll
    for (int n = 0; n < 8; ++n)
        #pragma unroll
        for (int c = 0; c < 4; ++c) acc[n][c] = 0.0f;

    #pragma unroll 1
    for (int s = 0; s < 4; ++s) {
        const float* src  = (s < 2) ? agg : x;
        const float* Wsrc = (s < 2) ? W_l : W_r;
        const int    k0   = (s & 1) * BK;

        __syncthreads();

        #pragma unroll
        for (int q = 0; q < 4; ++q) {
            const int idx  = t + 256 * q;
            const int node = idx >> 3;
            const int kq   = (idx & 7) * 4;
            float4 v = make_float4(0.f, 0.f, 0.f, 0.f);
            if (base + node < n_nodes)
                v = *(const float4*)(src + (size_t)(base + node) * D + k0 + kq);
            AT[kq + 0][node] = v.x;
            AT[kq + 1][node] = v.y;
            AT[kq + 2][node] = v.z;
            AT[kq + 3][node] = v.w;
        }
        #pragma unroll
        for (int q = 0; q < 2; ++q) {
            const int idx = t + 256 * q;
            const int kk  = idx >> 4;
            const int cq  = (idx & 15) * 4;
            *(float4*)&Wt[kk][cq] = *(const float4*)(Wsrc + (size_t)(k0 + kk) * D + cq);
        }
        __syncthreads();

        #pragma unroll 4
        for (int kk = 0; kk < BK; ++kk) {
            float4 a0 = *(const float4*)&AT[kk][tm * 8];
            float4 a1 = *(const float4*)&AT[kk][tm * 8 + 4];
            float4 w  = *(const float4*)&Wt[kk][to * 4];
            acc[0][0] += a0.x * w.x; acc[0][1] += a0.x * w.y; acc[0][2] += a0.x * w.z; acc[0][3] += a0.x * w.w;
            acc[1][0] += a0.y * w.x; acc[1][1] += a0.y * w.y; acc[1][2] += a0.y * w.z; acc[1][3] += a0.y * w.w;
            acc[2][0] += a0.z * w.x; acc[2][1] += a0.z * w.y; acc[2][2] += a0.z * w.z; acc[2][3] += a0.z * w.w;
            acc[3][0] += a0.w * w.x; acc[3][1] += a0.w * w.y; acc[3][2] += a0.w * w.z; acc[3][3] += a0.w * w.w;
            acc[4][0] += a1.x * w.x; acc[4][1] += a1.x * w.y; acc[4][2] += a1.x * w.z; acc[4][3] += a1.x * w.w;
            acc[5][0] += a1.y * w.x; acc[5][1] += a1.y * w.y; acc[5][2] += a1.y * w.z; acc[5][3] += a1.y * w.w;
            acc[6][0] += a1.z * w.x; acc[6][1] += a1.z * w.y; acc[6][2] += a1.z * w.z; acc[6][3] += a1.z * w.w;
            acc[7][0] += a1.w * w.x; acc[7][1] += a1.w * w.y; acc[7][2] += a1.w * w.z; acc[7][3] += a1.w * w.w;
        }
    }

    const float4 bb = *(const float4*)(b_l + to * 4);
    #pragma unroll
    for (int n = 0; n < 8; ++n) {
        const int node = base + tm * 8 + n;
        if (node < n_nodes) {
            float4 r = make_float4(acc[n][0] + bb.x, acc[n][1] + bb.y,
                                   acc[n][2] + bb.z, acc[n][3] + bb.w);
            *(float4*)(out + (size_t)node * D + to * 4) = r;
        }
    }
}

// ---------------------------------------------------------------------------
extern "C" void kernel_launch(void* const* d_in, const int* in_sizes, int n_in,
                              void* d_out, int out_size, void* d_ws, size_t ws_size,
                              hipStream_t stream)
{
    const float* x         = (const float*)d_in[0];
    const float* edge_attr = (const float*)d_in[1];
    const float* W_e       = (const float*)d_in[2];
    const float* b_e       = (const float*)d_in[3];
    const float* W_l       = (const float*)d_in[4];
    const float* b_l       = (const float*)d_in[5];
    const float* W_r       = (const float*)d_in[6];
    const void*  edge_index= d_in[7];

    const int n_nodes = in_sizes[0] / D;
    const int n_edges = in_sizes[1] / ED;

    float* out = (float*)d_out;

    // workspace layout (bytes); offs gets n+1 entries (sentinel)
    const size_t n_align = ((size_t)n_nodes + 255) & ~(size_t)255;
    const int    NB      = (n_nodes + 255) / 256;       // scan blocks
    const size_t o_cnt   = 0;
    const size_t o_offs  = o_cnt  + n_align * 4;
    const size_t o_cur   = o_offs + n_align * 4 + 256;  // +256: sentinel room
    const size_t o_bsum  = o_cur  + n_align * 4;
    const size_t o_pair  = (o_bsum + (size_t)NB * 4 + 255) & ~(size_t)255;
    const size_t need    = o_pair + (size_t)n_edges * 8;

    if (need <= ws_size && NB <= 1024) {
        int*  cnt    = (int*)((char*)d_ws + o_cnt);
        int*  offs   = (int*)((char*)d_ws + o_offs);
        int*  cursor = (int*)((char*)d_ws + o_cur);
        int*  bsum   = (int*)((char*)d_ws + o_bsum);
        int2* pair   = (int2*)((char*)d_ws + o_pair);

        // single cooperative dispatch: zero + count + scan + scatter
        void* ei = (void*)edge_index;
        int nn = n_nodes, ne = n_edges;
        void* args[] = { &ei, &cnt, &offs, &cursor, &bsum, &pair, &nn, &ne };
        hipLaunchCooperativeKernel((void*)csr_build_kernel,
                                   dim3(1024), dim3(256), args, 0, stream);

        reduce_kernel<<<2048, 256, 0, stream>>>(
            x, edge_attr, W_e, b_e, pair, offs, out, n_nodes);
    } else {
        // fallback: atomic scatter path + divide
        float* cntf = (float*)((char*)d_ws + o_cnt);
        hipMemsetAsync(out, 0, (size_t)out_size * sizeof(float), stream);
        hipMemsetAsync(cntf, 0, (size_t)n_nodes * sizeof(float), stream);
        edge_scatter_kernel<<<4096, 256, 0, stream>>>(
            x, edge_attr, W_e, b_e, edge_index, out, cntf, n_edges);
        divide_kernel<<<(n_nodes * D + 255) / 256, 256, 0, stream>>>(out, cntf, n_nodes);
    }

    node_gemm_kernel<<<(n_nodes + BM - 1) / BM, 256, 0, stream>>>(
        x, out, W_l, b_l, W_r, out, n_nodes);
}

// Round 15
// 278.294 us; speedup vs baseline: 2.1927x; 2.1927x over previous
//
#include <hip/hip_runtime.h>

#define D 64
#define ED 16

// ---------------------------------------------------------------------------
// Inline int64/int32 probe (wave-uniform): int64 nonneg indices -> all odd
// dwords zero.  P(false positive on int32 random indices) ~ 0.
// ---------------------------------------------------------------------------
__device__ __forceinline__ int detect_is64(const int* __restrict__ idx32)
{
    int v = idx32[2 * (threadIdx.x & 63) + 1];
    return __all(v == 0) ? 1 : 0;
}

__device__ __forceinline__ int load_idx(const void* p, size_t i, int is64)
{
    return is64 ? (int)((const long long*)p)[i] : ((const int*)p)[i];
}

// ---------------------------------------------------------------------------
// CSR build step 1: per-destination degree count (1 int atomic per edge).
// ---------------------------------------------------------------------------
__global__ void __launch_bounds__(256)
count_kernel(const void* __restrict__ edge_index, int* __restrict__ cnt, int n_edges)
{
    const int is64 = detect_is64((const int*)edge_index);
    const int stride = gridDim.x * blockDim.x;
    for (int e = blockIdx.x * blockDim.x + threadIdx.x; e < n_edges; e += stride) {
        int dst = load_idx(edge_index, (size_t)n_edges + e, is64);
        atomicAdd(&cnt[dst], 1);
    }
}

// ---------------------------------------------------------------------------
// CSR build step 2 (round-15): SINGLE-dispatch scan via aggregate-only
// decoupled lookback.  Each block: local inclusive scan; publish block total
// bsum[b] with an agent-scope release flag; then sum predecessors' totals
// (no serial chain — every aggregate is ready right after its local scan).
// Replaces the scan1+scan3 pair (one fewer dispatch + pipeline drain).
// NOTE: grid.sync() is NOT used — round-14 measured ~120 us per grid sync.
// flags[] zeroed by the same memset as cnt.  391 blocks trivially
// co-resident -> spin cannot deadlock.
// ---------------------------------------------------------------------------
__global__ void __launch_bounds__(256)
scan_kernel(const int* __restrict__ cnt, int* __restrict__ offs,
            int* __restrict__ cursor, int* __restrict__ bsum,
            int* __restrict__ flags, int n, int n_edges)
{
    __shared__ int sd[256];
    const int t = threadIdx.x;
    const int b = blockIdx.x;
    const int i = b * 256 + t;

    int v = (i < n) ? cnt[i] : 0;
    sd[t] = v;
    __syncthreads();
    for (int off = 1; off < 256; off <<= 1) {
        int add = (t >= off) ? sd[t - off] : 0;
        __syncthreads();
        sd[t] += add;
        __syncthreads();
    }
    const int excl = sd[t] - v;              // exclusive within block

    // publish this block's total (release: bsum write ordered before flag)
    if (t == 255) {
        bsum[b] = sd[255];
        __hip_atomic_store(&flags[b], 1, __ATOMIC_RELEASE, __HIP_MEMORY_SCOPE_AGENT);
    }

    // lookback: sum all predecessor block totals (parallel across threads)
    int part = 0;
    for (int j = t; j < b; j += 256) {
        while (__hip_atomic_load(&flags[j], __ATOMIC_ACQUIRE,
                                 __HIP_MEMORY_SCOPE_AGENT) == 0) { }
        part += bsum[j];
    }
    __syncthreads();                         // sd free for reuse
    sd[t] = part;
    __syncthreads();
    for (int off = 128; off > 0; off >>= 1) {
        if (t < off) sd[t] += sd[t + off];
        __syncthreads();
    }
    const int S = sd[0];

    if (i < n) {
        int o = excl + S;
        offs[i]   = o;
        cursor[i] = o;
    }
    if (b == 0 && t == 0) offs[n] = n_edges; // sentinel: deg = offs[i+1]-offs[i]
}

// ---------------------------------------------------------------------------
// CSR build step 3: scatter (src, eid) pairs to sorted-by-dst positions.
// ---------------------------------------------------------------------------
__global__ void __launch_bounds__(256)
scatter_kernel(const void* __restrict__ edge_index,
               int* __restrict__ cursor, int2* __restrict__ pair, int n_edges)
{
    const int is64 = detect_is64((const int*)edge_index);
    const int stride = gridDim.x * blockDim.x;
    for (int e = blockIdx.x * blockDim.x + threadIdx.x; e < n_edges; e += stride) {
        int src = load_idx(edge_index, e, is64);
        int dst = load_idx(edge_index, (size_t)n_edges + e, is64);
        int pos = atomicAdd(&cursor[dst], 1);
        pair[pos] = make_int2(src, e);
    }
}

// ---------------------------------------------------------------------------
// Gather-reduce — EXACT round-9 structure (measured 97 us, VGPR 40; proven
// floor: invariant to bytes/lines/occupancy/MLP-depth — L3 random-line
// service bound).  One wave per node, grid-strided, no LDS, no barriers,
// W_e column in 16 VGPRs/lane.
//   agg_mean[i] = ( sum_e x[src_e] + (sum_e ea[e]) @ W_e + deg*b_e ) / max(deg,1)
// ---------------------------------------------------------------------------
__global__ void __launch_bounds__(256)
reduce_kernel(const float* __restrict__ x,
              const float* __restrict__ edge_attr,
              const float* __restrict__ W_e,
              const float* __restrict__ b_e,
              const int2* __restrict__ pair,
              const int* __restrict__ offs,   // n_nodes+1 (sentinel)
              float* __restrict__ agg,
              int n_nodes)
{
    const int lane = threadIdx.x & 63;
    const int wid  = threadIdx.x >> 6;
    const int sub  = lane >> 4;
    const int k16  = lane & 15;

    float Wreg[ED];
    #pragma unroll
    for (int k = 0; k < ED; ++k) Wreg[k] = W_e[k * D + lane];
    const float beL = b_e[lane];

    const int nstride = gridDim.x * 4;
    for (int node = blockIdx.x * 4 + wid; node < n_nodes; node += nstride) {
        const int beg = offs[node];
        const int deg = offs[node + 1] - beg;

        float xs  = 0.0f;
        float eas = 0.0f;

        for (int j0 = 0; j0 < deg; j0 += 16) {
            const int nb = min(16, deg - j0);       // wave-uniform
            int2 p = make_int2(0, 0);
            if (lane < nb) p = pair[beg + j0 + lane];

            float t[16];
            #pragma unroll
            for (int m = 0; m < 16; ++m) {
                int s = __shfl(p.x, m);
                t[m] = (m < nb) ? x[(size_t)s * D + lane] : 0.0f;
            }

            #pragma unroll
            for (int mm = 0; mm < 4; ++mm) {
                int m = sub + 4 * mm;
                int eid = __shfl(p.y, m);
                if (m < nb) eas += edge_attr[(size_t)eid * ED + k16];
            }

            #pragma unroll
            for (int m = 0; m < 16; ++m) xs += t[m];
        }

        float ea2 = eas + __shfl_xor(eas, 16);
        ea2 += __shfl_xor(ea2, 32);

        float acc = xs + (float)deg * beL;
        #pragma unroll
        for (int k = 0; k < ED; ++k)
            acc += __shfl(ea2, k) * Wreg[k];

        agg[(size_t)node * D + lane] = acc * (1.0f / fmaxf((float)deg, 1.0f));
    }
}

// ---------------------------------------------------------------------------
// Fallback path (ws too small): atomic scatter + divide.
// ---------------------------------------------------------------------------
__global__ void __launch_bounds__(256)
edge_scatter_kernel(const float* __restrict__ x,
                    const float* __restrict__ edge_attr,
                    const float* __restrict__ W_e,
                    const float* __restrict__ b_e,
                    const void* __restrict__ edge_index,
                    float* __restrict__ agg,
                    float* __restrict__ cnt,
                    int n_edges)
{
    __shared__ float We[ED * D];
    __shared__ float be[D];
    for (int i = threadIdx.x; i < ED * D; i += blockDim.x) We[i] = W_e[i];
    if (threadIdx.x < D) be[threadIdx.x] = b_e[threadIdx.x];
    __syncthreads();

    const int is64 = detect_is64((const int*)edge_index);
    const int lane = threadIdx.x & 63;
    const int wid  = threadIdx.x >> 6;
    const int estr = gridDim.x * 4;

    for (int e = blockIdx.x * 4 + wid; e < n_edges; e += estr) {
        int src = load_idx(edge_index, e, is64);
        int dst = load_idx(edge_index, (size_t)n_edges + e, is64);
        const float4* ea = (const float4*)(edge_attr + (size_t)e * ED);
        float4 e0 = ea[0], e1 = ea[1], e2 = ea[2], e3 = ea[3];

        float m = be[lane] + x[(size_t)src * D + lane];
        m += e0.x * We[ 0*D + lane] + e0.y * We[ 1*D + lane]
           + e0.z * We[ 2*D + lane] + e0.w * We[ 3*D + lane];
        m += e1.x * We[ 4*D + lane] + e1.y * We[ 5*D + lane]
           + e1.z * We[ 6*D + lane] + e1.w * We[ 7*D + lane];
        m += e2.x * We[ 8*D + lane] + e2.y * We[ 9*D + lane]
           + e2.z * We[10*D + lane] + e2.w * We[11*D + lane];
        m += e3.x * We[12*D + lane] + e3.y * We[13*D + lane]
           + e3.z * We[14*D + lane] + e3.w * We[15*D + lane];

        atomicAdd(&agg[(size_t)dst * D + lane], m);
        if (lane == 0) atomicAdd(&cnt[dst], 1.0f);
    }
}

__global__ void divide_kernel(float* __restrict__ agg, const float* __restrict__ cnt, int n_nodes)
{
    const int i = blockIdx.x * 256 + threadIdx.x;
    if (i < n_nodes * D) {
        float c = cnt[i >> 6];
        agg[i] *= 1.0f / fmaxf(c, 1.0f);
    }
}

// ---------------------------------------------------------------------------
// Node phase as one GEMM:  out = [agg | x] @ [W_l ; W_r] + b_l
// (register discipline per round-5 lesson: rolled s-loop, unroll 4 kk-loop,
//  __launch_bounds__(256,4) caps VGPR at 128.)  UNCHANGED (proven ~40 us).
// ---------------------------------------------------------------------------
#define BM 128
#define BK 32
#define ATP 132   // padded row length (dwords): 132*4B % 16B == 0

__global__ void __launch_bounds__(256, 4)
node_gemm_kernel(const float* x,
                 const float* agg,                // == out (in-place)
                 const float* __restrict__ W_l,
                 const float* __restrict__ b_l,
                 const float* __restrict__ W_r,
                 float* out,
                 int n_nodes)
{
    __shared__ float AT[BK][ATP];
    __shared__ float Wt[BK][D];

    const int t   = threadIdx.x;
    const int to  = t & 15;
    const int tm  = t >> 4;
    const int base = blockIdx.x * BM;

    float acc[8][4];
    #pragma unroll
    for (int n = 0; n < 8; ++n)
        #pragma unroll
        for (int c = 0; c < 4; ++c) acc[n][c] = 0.0f;

    #pragma unroll 1
    for (int s = 0; s < 4; ++s) {
        const float* src  = (s < 2) ? agg : x;
        const float* Wsrc = (s < 2) ? W_l : W_r;
        const int    k0   = (s & 1) * BK;

        __syncthreads();

        #pragma unroll
        for (int q = 0; q < 4; ++q) {
            const int idx  = t + 256 * q;
            const int node = idx >> 3;
            const int kq   = (idx & 7) * 4;
            float4 v = make_float4(0.f, 0.f, 0.f, 0.f);
            if (base + node < n_nodes)
                v = *(const float4*)(src + (size_t)(base + node) * D + k0 + kq);
            AT[kq + 0][node] = v.x;
            AT[kq + 1][node] = v.y;
            AT[kq + 2][node] = v.z;
            AT[kq + 3][node] = v.w;
        }
        #pragma unroll
        for (int q = 0; q < 2; ++q) {
            const int idx = t + 256 * q;
            const int kk  = idx >> 4;
            const int cq  = (idx & 15) * 4;
            *(float4*)&Wt[kk][cq] = *(const float4*)(Wsrc + (size_t)(k0 + kk) * D + cq);
        }
        __syncthreads();

        #pragma unroll 4
        for (int kk = 0; kk < BK; ++kk) {
            float4 a0 = *(const float4*)&AT[kk][tm * 8];
            float4 a1 = *(const float4*)&AT[kk][tm * 8 + 4];
            float4 w  = *(const float4*)&Wt[kk][to * 4];
            acc[0][0] += a0.x * w.x; acc[0][1] += a0.x * w.y; acc[0][2] += a0.x * w.z; acc[0][3] += a0.x * w.w;
            acc[1][0] += a0.y * w.x; acc[1][1] += a0.y * w.y; acc[1][2] += a0.y * w.z; acc[1][3] += a0.y * w.w;
            acc[2][0] += a0.z * w.x; acc[2][1] += a0.z * w.y; acc[2][2] += a0.z * w.z; acc[2][3] += a0.z * w.w;
            acc[3][0] += a0.w * w.x; acc[3][1] += a0.w * w.y; acc[3][2] += a0.w * w.z; acc[3][3] += a0.w * w.w;
            acc[4][0] += a1.x * w.x; acc[4][1] += a1.x * w.y; acc[4][2] += a1.x * w.z; acc[4][3] += a1.x * w.w;
            acc[5][0] += a1.y * w.x; acc[5][1] += a1.y * w.y; acc[5][2] += a1.y * w.z; acc[5][3] += a1.y * w.w;
            acc[6][0] += a1.z * w.x; acc[6][1] += a1.z * w.y; acc[6][2] += a1.z * w.z; acc[6][3] += a1.z * w.w;
            acc[7][0] += a1.w * w.x; acc[7][1] += a1.w * w.y; acc[7][2] += a1.w * w.z; acc[7][3] += a1.w * w.w;
        }
    }

    const float4 bb = *(const float4*)(b_l + to * 4);
    #pragma unroll
    for (int n = 0; n < 8; ++n) {
        const int node = base + tm * 8 + n;
        if (node < n_nodes) {
            float4 r = make_float4(acc[n][0] + bb.x, acc[n][1] + bb.y,
                                   acc[n][2] + bb.z, acc[n][3] + bb.w);
            *(float4*)(out + (size_t)node * D + to * 4) = r;
        }
    }
}

// ---------------------------------------------------------------------------
extern "C" void kernel_launch(void* const* d_in, const int* in_sizes, int n_in,
                              void* d_out, int out_size, void* d_ws, size_t ws_size,
                              hipStream_t stream)
{
    const float* x         = (const float*)d_in[0];
    const float* edge_attr = (const float*)d_in[1];
    const float* W_e       = (const float*)d_in[2];
    const float* b_e       = (const float*)d_in[3];
    const float* W_l       = (const float*)d_in[4];
    const float* b_l       = (const float*)d_in[5];
    const float* W_r       = (const float*)d_in[6];
    const void*  edge_index= d_in[7];

    const int n_nodes = in_sizes[0] / D;
    const int n_edges = in_sizes[1] / ED;

    float* out = (float*)d_out;

    // workspace layout (bytes); offs gets n+1 entries (sentinel);
    // flags adjacent to cnt so ONE memset zeroes both.
    const size_t n_align = ((size_t)n_nodes + 255) & ~(size_t)255;
    const int    NB      = (n_nodes + 255) / 256;       // scan blocks
    const size_t NBal    = ((size_t)NB * 4 + 255) & ~(size_t)255;
    const size_t o_cnt   = 0;
    const size_t o_flag  = n_align * 4;                 // NBal bytes
    const size_t o_offs  = o_flag + NBal;
    const size_t o_cur   = o_offs + n_align * 4 + 256;  // +256: sentinel room
    const size_t o_bsum  = o_cur  + n_align * 4;
    const size_t o_pair  = (o_bsum + NBal + 255) & ~(size_t)255;
    const size_t need    = o_pair + (size_t)n_edges * 8;

    if (need <= ws_size && NB <= 2048) {
        int*  cnt    = (int*)((char*)d_ws + o_cnt);
        int*  flags  = (int*)((char*)d_ws + o_flag);
        int*  offs   = (int*)((char*)d_ws + o_offs);
        int*  cursor = (int*)((char*)d_ws + o_cur);
        int*  bsum   = (int*)((char*)d_ws + o_bsum);
        int2* pair   = (int2*)((char*)d_ws + o_pair);

        hipMemsetAsync(cnt, 0, n_align * 4 + NBal, stream);   // cnt + flags

        count_kernel<<<2048, 256, 0, stream>>>(edge_index, cnt, n_edges);
        scan_kernel<<<NB, 256, 0, stream>>>(cnt, offs, cursor, bsum, flags,
                                            n_nodes, n_edges);
        scatter_kernel<<<2048, 256, 0, stream>>>(edge_index, cursor, pair, n_edges);
        reduce_kernel<<<2048, 256, 0, stream>>>(
            x, edge_attr, W_e, b_e, pair, offs, out, n_nodes);
    } else {
        // fallback: atomic scatter path + divide
        float* cntf = (float*)((char*)d_ws + o_cnt);
        hipMemsetAsync(out, 0, (size_t)out_size * sizeof(float), stream);
        hipMemsetAsync(cntf, 0, (size_t)n_nodes * sizeof(float), stream);
        edge_scatter_kernel<<<4096, 256, 0, stream>>>(
            x, edge_attr, W_e, b_e, edge_index, out, cntf, n_edges);
        divide_kernel<<<(n_nodes * D + 255) / 256, 256, 0, stream>>>(out, cntf, n_nodes);
    }

    node_gemm_kernel<<<(n_nodes + BM - 1) / BM, 256, 0, stream>>>(
        x, out, W_l, b_l, W_r, out, n_nodes);
}